// Round 1
// 2661.296 us; speedup vs baseline: 1.2015x; 1.2015x over previous
//
#include <hip/hip_runtime.h>

// Problem constants (AttentionSpeller): T=128, B=32, E=H=512, U=1024, V=10000
#define T_STEPS 128
#define BATCH   32
#define HID     512
#define EMB     512
#define ULEN    1024
#define VOCAB   10000
#define G4H     2048   // 4*H

// Barrier region: 256 arrive words (stride 16 u32 = 64 B) + 32 go words
// (stride 64 u32 = 256 B). 6144 u32 per scan, two scans.
#define ARR_STRIDE 16
#define GO_OFF     4096
#define GO_STRIDE  64
#define BAR_WORDS  6144

static inline int cdiv(int a, int b) { return (a + b - 1) / b; }

// ---------------------------------------------------------------------------
// Generic tiled fp32 GEMM: C[M,N] = A[M,K] * op(B) (+ bias[N])
//   TRANSB=true : B is [N,K] row-major (C = A * B^T)
//   TRANSB=false: B is [K,N] row-major (C = A * B)
// Batched via blockIdx.z with element strides sA/sB/sC.
// Assumes: M % 64 == 0, K % 16 == 0. N guarded (for V=10000).
// ---------------------------------------------------------------------------
template <bool TRANSB>
__global__ __launch_bounds__(256)
void gemm_f32(const float* __restrict__ A, long lda, long sA,
              const float* __restrict__ Bm, long ldb, long sB,
              float* __restrict__ C, long ldc, long sC,
              int M, int N, int K, const float* __restrict__ bias)
{
    __shared__ float As[16][68];
    __shared__ float Bs[16][68];
    const int bz = blockIdx.z;
    A  += (size_t)bz * sA;
    Bm += (size_t)bz * sB;
    C  += (size_t)bz * sC;
    const int m0 = blockIdx.y * 64;
    const int n0 = blockIdx.x * 64;
    const int tid = threadIdx.x;
    const int tx = tid & 15, ty = tid >> 4;
    const int lr = tid >> 2;          // 0..63: tile row
    const int lk = (tid & 3) * 4;     // 0,4,8,12: k offset

    float acc[4][4] = {{0.f}};

    for (int k0 = 0; k0 < K; k0 += 16) {
        float4 av = *(const float4*)(A + (size_t)(m0 + lr) * lda + (k0 + lk));
        As[lk + 0][lr] = av.x; As[lk + 1][lr] = av.y;
        As[lk + 2][lr] = av.z; As[lk + 3][lr] = av.w;
        if (TRANSB) {
            const int nr = n0 + lr;
            float4 bv = make_float4(0.f, 0.f, 0.f, 0.f);
            if (nr < N) bv = *(const float4*)(Bm + (size_t)nr * ldb + (k0 + lk));
            Bs[lk + 0][lr] = bv.x; Bs[lk + 1][lr] = bv.y;
            Bs[lk + 2][lr] = bv.z; Bs[lk + 3][lr] = bv.w;
        } else {
            const int kr = tid >> 4;          // 0..15
            const int nc = (tid & 15) * 4;    // 0..60
            float4 bv = make_float4(0.f, 0.f, 0.f, 0.f);
            if (n0 + nc < N) bv = *(const float4*)(Bm + (size_t)(k0 + kr) * ldb + (n0 + nc));
            *(float4*)&Bs[kr][nc] = bv;
        }
        __syncthreads();
#pragma unroll
        for (int kk = 0; kk < 16; ++kk) {
            float ar[4], br[4];
#pragma unroll
            for (int i = 0; i < 4; i++) ar[i] = As[kk][ty * 4 + i];
#pragma unroll
            for (int j = 0; j < 4; j++) br[j] = Bs[kk][tx * 4 + j];
#pragma unroll
            for (int i = 0; i < 4; i++)
#pragma unroll
                for (int j = 0; j < 4; j++)
                    acc[i][j] += ar[i] * br[j];
        }
        __syncthreads();
    }
#pragma unroll
    for (int i = 0; i < 4; i++) {
        const int row = m0 + ty * 4 + i;
#pragma unroll
        for (int j = 0; j < 4; j++) {
            const int col = n0 + tx * 4 + j;
            if (col < N) {
                float v = acc[i][j];
                if (bias) v += bias[col];
                C[(size_t)row * ldc + col] = v;
            }
        }
    }
}

// ---------------------------------------------------------------------------
// Persistent LSTM scan v4 — W_hh in registers + k-split dot.
//
// 256 blocks (1/CU), 256 threads. Block bid owns h columns {2bid, 2bid+1}
// = gate columns n = g*512 + 2bid + j.
//
// v3 post-mortem: dot phase read BOTH operands from LDS (256 ds_read_b128
// per thread per step); the W half re-read the same 2 KB row all 128 steps
// -> LDS pipe was the largest per-step cost (~3.4us of 7.75us). v4:
//  - dot-phase remap: tid = ks*8 + nc (32 k-slices x 8 columns). Each
//    thread holds W[n(nc)][ks*16..+15] in 16 VGPRs, loaded ONCE. W LDS
//    traffic eliminated; h reads halve to 128 b128/thread/step.
//  - h_lds f4-swizzle p = f ^ ((f>>2)&7): bijective per 128-f4 row; the 8
//    ks-lanes of an instruction land on 8 distinct bank-quads (8-way nc
//    broadcast) -> conflict-free reads AND writes.
//  - ks-reduction via part[256*36] (stride 36 floats: write bank-quad =
//    (tid+i)&7, conflict-free; strided b32 reads <=2-way = free).
//  - barrier + h staging + cell phase unchanged from v3 (proven correct).
// ---------------------------------------------------------------------------
__device__ inline float sigmoidf_(float x) { return 1.f / (1.f + expf(-x)); }

__global__ __launch_bounds__(256, 1)
void lstm_scan(const float* __restrict__ gp,    // (T*B*2048) x@W_ih^T + b_ih + b_hh
               const float* __restrict__ Whh,   // (2048 x 512) row-major
               const float* __restrict__ h0,    // (B*H) layer slice
               const float* __restrict__ c0,    // (B*H) layer slice
               float* __restrict__ h_all,       // (T*B*H) out
               unsigned* __restrict__ bar)      // zeroed barrier region
{
    __shared__ float h_lds[BATCH * HID];        // 64 KB, XOR-swizzled float4s
    __shared__ float part[256 * 36];            // 36 KB partial sums
    unsigned* arrive = bar;
    unsigned* go     = bar + GO_OFF;

    const int tid  = threadIdx.x;
    const int bid  = blockIdx.x;
    const int hbase = bid * 2;

    // dot-phase identity: tid = ks*8 + nc
    const int ks = tid >> 3;                    // 0..31 k-slice of 16
    const int nc = tid & 7;                     // 0..7 gate column
    const int kl = ks & 7;

    // cell-phase identity: tid = b*8 + nl
    const int b    = tid >> 3;                  // 0..31
    const int nl   = tid & 7;                   // 0..7
    const int j    = nl & 1;
    const int lane = tid & 63;
    const int sbase = lane & ~7;                // shuffle group base lane
    const int n = ((nl >> 1) << 9) + hbase + j; // gate column 0..2047

    // ---- W slice -> 16 VGPRs, persistent across all 128 steps ----
    float4 w0, w1, w2, w3;
    {
        const int nd = ((nc >> 1) << 9) + hbase + (nc & 1);
        const float4* wsrc = (const float4*)(Whh + (size_t)nd * HID + ks * 16);
        w0 = wsrc[0]; w1 = wsrc[1]; w2 = wsrc[2]; w3 = wsrc[3];
    }

    // 4 swizzled LDS base pointers for this thread's k-slice
    const float* hp0 = h_lds + ((((ks * 4 + 0) ^ kl)) << 2);
    const float* hp1 = h_lds + ((((ks * 4 + 1) ^ kl)) << 2);
    const float* hp2 = h_lds + ((((ks * 4 + 2) ^ kl)) << 2);
    const float* hp3 = h_lds + ((((ks * 4 + 3) ^ kl)) << 2);

    float c_state = (nl < 2) ? c0[b * HID + hbase + j] : 0.f;

    for (int t = 0; t < T_STEPS; ++t) {
        // h-independent gate preactivation (hide under staging)
        float gval = gp[((size_t)t * BATCH + b) * G4H + n];

        // ---- stage h(t-1) -> LDS (plain cached float4 loads) ----
        const float* hsrc = (t == 0) ? h0 : (h_all + (size_t)(t - 1) * (BATCH * HID));
#pragma unroll
        for (int i = 0; i < 16; ++i) {
            const int vi = i * 256 + tid;       // float4 index 0..4095
            float4 v = *(const float4*)(hsrc + (size_t)vi * 4);
            const int bb = vi >> 7;             // batch row
            const int f  = vi & 127;            // f4 within row
            const int p  = f ^ ((f >> 2) & 7);  // swizzled slot (bijective)
            *(float4*)&h_lds[(bb << 9) + (p << 2)] = v;
        }
        __syncthreads();

        // ---- partial dots: acc[b2] = h[b2][ks*16..+15] . Wreg ----
        float acc[32];
#pragma unroll
        for (int b2 = 0; b2 < 32; ++b2) {
            const int o = b2 << 9;              // 2048 B row stride (imm-foldable)
            float4 ha = *(const float4*)(hp0 + o);
            float4 hb = *(const float4*)(hp1 + o);
            float4 hc = *(const float4*)(hp2 + o);
            float4 hd = *(const float4*)(hp3 + o);
            acc[b2] = (ha.x * w0.x + ha.y * w0.y + ha.z * w0.z + ha.w * w0.w)
                    + (hb.x * w1.x + hb.y * w1.y + hb.z * w1.z + hb.w * w1.w)
                    + (hc.x * w2.x + hc.y * w2.y + hc.z * w2.z + hc.w * w2.w)
                    + (hd.x * w3.x + hd.y * w3.y + hd.z * w3.z + hd.w * w3.w);
        }
        {
            float* pw = &part[tid * 36];
#pragma unroll
            for (int i = 0; i < 8; ++i)
                *(float4*)(pw + i * 4) =
                    make_float4(acc[4 * i], acc[4 * i + 1], acc[4 * i + 2], acc[4 * i + 3]);
        }
        __syncthreads();

        // ---- reduce over ks; thread (b,nl) owns output column n ----
        float s = gval;
        {
            const float* pr = &part[nl * 36 + b];
#pragma unroll
            for (int kr = 0; kr < 32; ++kr) s += pr[kr * 288];
        }

        // ---- cell: exchange f/g/o via shuffles; owners nl in {0,1} ----
        float fva = __shfl(s, sbase + 2 + j);
        float gva = __shfl(s, sbase + 4 + j);
        float ova = __shfl(s, sbase + 6 + j);
        if (nl < 2) {
            float iv = sigmoidf_(s);
            float fv = sigmoidf_(fva);
            float gv = tanhf(gva);
            float ov = sigmoidf_(ova);
            c_state = fv * c_state + iv * gv;
            float hn = ov * tanhf(c_state);
            // write-through store (agent scope) -> visible at coherence point
            __hip_atomic_store(h_all + ((size_t)t * BATCH + b) * HID + hbase + j,
                               hn, __ATOMIC_RELAXED, __HIP_MEMORY_SCOPE_AGENT);
        }

        // ---- grid barrier: syncthreads drains the h stores first ----
        __syncthreads();
        const unsigned want = (unsigned)(t + 1);
        if (bid == 0) {
            if (tid == 0)
                __hip_atomic_store(&arrive[0], want, __ATOMIC_RELAXED,
                                   __HIP_MEMORY_SCOPE_AGENT);
            unsigned v;
            do {
                v = __hip_atomic_load(&arrive[tid * ARR_STRIDE], __ATOMIC_RELAXED,
                                      __HIP_MEMORY_SCOPE_AGENT);
            } while (__syncthreads_count(v >= want) < 256);
            if (tid < 32)
                __hip_atomic_store(&go[tid * GO_STRIDE], want, __ATOMIC_RELAXED,
                                   __HIP_MEMORY_SCOPE_AGENT);
        } else if (tid == 0) {
            __hip_atomic_store(&arrive[bid * ARR_STRIDE], want, __ATOMIC_RELAXED,
                               __HIP_MEMORY_SCOPE_AGENT);
            unsigned g;
            do {
                __builtin_amdgcn_s_sleep(1);
                g = __hip_atomic_load(&go[(bid & 31) * GO_STRIDE], __ATOMIC_RELAXED,
                                      __HIP_MEMORY_SCOPE_AGENT);
            } while (g < want);
        }
        __syncthreads();
    }
}

// ---------------------------------------------------------------------------
// Softmax over U=1024 (attention weights), in place. One block per (t,b) row.
// ---------------------------------------------------------------------------
__device__ inline float warpReduceMax_(float v) {
#pragma unroll
    for (int o = 32; o > 0; o >>= 1) v = fmaxf(v, __shfl_xor(v, o));
    return v;
}
__device__ inline float warpReduceSum_(float v) {
#pragma unroll
    for (int o = 32; o > 0; o >>= 1) v += __shfl_xor(v, o);
    return v;
}
__device__ inline float blockReduceMax_(float v, float* red) {
    v = warpReduceMax_(v);
    if ((threadIdx.x & 63) == 0) red[threadIdx.x >> 6] = v;
    __syncthreads();
    float r = fmaxf(fmaxf(red[0], red[1]), fmaxf(red[2], red[3]));
    __syncthreads();
    return r;
}
__device__ inline float blockReduceSum_(float v, float* red) {
    v = warpReduceSum_(v);
    if ((threadIdx.x & 63) == 0) red[threadIdx.x >> 6] = v;
    __syncthreads();
    float r = (red[0] + red[1]) + (red[2] + red[3]);
    __syncthreads();
    return r;
}

__global__ __launch_bounds__(256)
void softmax_u(float* __restrict__ s)
{
    __shared__ float red[4];
    float4* p = (float4*)(s + (size_t)blockIdx.x * ULEN);
    float4 v = p[threadIdx.x];
    float mx = fmaxf(fmaxf(v.x, v.y), fmaxf(v.z, v.w));
    mx = blockReduceMax_(mx, red);
    v.x = expf(v.x - mx); v.y = expf(v.y - mx);
    v.z = expf(v.z - mx); v.w = expf(v.w - mx);
    float sm = blockReduceSum_(v.x + v.y + v.z + v.w, red);
    float inv = 1.f / sm;
    v.x *= inv; v.y *= inv; v.z *= inv; v.w *= inv;
    p[threadIdx.x] = v;
}

// ---------------------------------------------------------------------------
// Softmax over V=10000 (output), in place. One block per (t,b) row.
// ---------------------------------------------------------------------------
__global__ __launch_bounds__(256)
void softmax_v(float* __restrict__ out)
{
    __shared__ float buf[VOCAB];
    __shared__ float red[4];
    float* p = out + (size_t)blockIdx.x * VOCAB;
    float mx = -INFINITY;
    for (int i = threadIdx.x; i < VOCAB; i += 256) {
        float x = p[i]; buf[i] = x; mx = fmaxf(mx, x);
    }
    mx = blockReduceMax_(mx, red);
    float sm = 0.f;
    for (int i = threadIdx.x; i < VOCAB; i += 256) {
        float e = expf(buf[i] - mx); buf[i] = e; sm += e;
    }
    sm = blockReduceSum_(sm, red);
    float inv = 1.f / sm;
    for (int i = threadIdx.x; i < VOCAB; i += 256) p[i] = buf[i] * inv;
}

// ---------------------------------------------------------------------------
// Prep: combined biases (b_ih + b_hh) + zero the barrier flag regions
// (ws is re-poisoned 0xAA before every call). Launch with 48 blocks.
// ---------------------------------------------------------------------------
__global__ void prep(const float* __restrict__ bi1, const float* __restrict__ bh1,
                     const float* __restrict__ bi2, const float* __restrict__ bh2,
                     float* __restrict__ bias1, float* __restrict__ bias2,
                     unsigned* __restrict__ flags)
{
    int i = blockIdx.x * 256 + threadIdx.x;
    if (i < G4H) { bias1[i] = bi1[i] + bh1[i]; bias2[i] = bi2[i] + bh2[i]; }
    if (i < 2 * BAR_WORDS) flags[i] = 0u;
}

// ---------------------------------------------------------------------------
extern "C" void kernel_launch(void* const* d_in, const int* in_sizes, int n_in,
                              void* d_out, int out_size, void* d_ws, size_t ws_size,
                              hipStream_t stream)
{
    const float* inputs = (const float*)d_in[0];   // (T,B,E)
    const float* h0     = (const float*)d_in[1];   // (2,B,H)
    const float* c0     = (const float*)d_in[2];   // (2,B,H)
    const float* L      = (const float*)d_in[3];   // (U,B,H)
    const float* W_ih1  = (const float*)d_in[4];   // (4H,E)
    const float* W_hh1  = (const float*)d_in[5];   // (4H,H)
    const float* b_ih1  = (const float*)d_in[6];
    const float* b_hh1  = (const float*)d_in[7];
    const float* W_ih2  = (const float*)d_in[8];   // (4H,H)
    const float* W_hh2  = (const float*)d_in[9];   // (4H,H)
    const float* b_ih2  = (const float*)d_in[10];
    const float* b_hh2  = (const float*)d_in[11];
    const float* W_out  = (const float*)d_in[12];  // (V,H)
    const float* b_out  = (const float*)d_in[13];  // (V)
    float* out = (float*)d_out;                    // (T,B,V) fp32

    // Workspace layout (~59 MB; scores aliases the dead pre-gates buffer)
    float* ws    = (float*)d_ws;
    float* gates = ws;                                        // T*B*4H
    float* h1    = gates + (size_t)T_STEPS * BATCH * G4H;     // T*B*H
    float* h2    = h1    + (size_t)T_STEPS * BATCH * HID;     // T*B*H
    float* ctx   = h2    + (size_t)T_STEPS * BATCH * HID;     // T*B*H
    float* bias1 = ctx   + (size_t)T_STEPS * BATCH * HID;     // 4H
    float* bias2 = bias1 + G4H;                               // 4H
    unsigned* flags = (unsigned*)(bias2 + G4H);               // 2*6144 u32
    float* scores = gates;                                    // alias (T,B,U)

    prep<<<48, 256, 0, stream>>>(b_ih1, b_hh1, b_ih2, b_hh2, bias1, bias2, flags);

    // X1 = inputs @ W_ih1^T + (b_ih1+b_hh1)   [4096 x 2048 x 512]
    gemm_f32<true><<<dim3(G4H / 64, (T_STEPS * BATCH) / 64, 1), 256, 0, stream>>>(
        inputs, EMB, 0, W_ih1, EMB, 0, gates, G4H, 0,
        T_STEPS * BATCH, G4H, EMB, bias1);

    // Layer-1 scan -> h1_all
    lstm_scan<<<256, 256, 0, stream>>>(gates, W_hh1, h0, c0, h1, flags);

    // scores[t,b,u] = h1[t,b,:] . L[u,b,:]   batched over b (NT GEMM)
    gemm_f32<true><<<dim3(ULEN / 64, T_STEPS / 64, BATCH), 256, 0, stream>>>(
        h1, (long)BATCH * HID, HID,
        L,  (long)BATCH * HID, HID,
        scores, (long)BATCH * ULEN, ULEN,
        T_STEPS, ULEN, HID, nullptr);

    softmax_u<<<T_STEPS * BATCH, 256, 0, stream>>>(scores);

    // ctx[t,b,h] = sum_u w[t,b,u] * L[u,b,h]  batched over b (NN GEMM, K=U)
    gemm_f32<false><<<dim3(HID / 64, T_STEPS / 64, BATCH), 256, 0, stream>>>(
        scores, (long)BATCH * ULEN, ULEN,
        L,      (long)BATCH * HID,  HID,
        ctx,    (long)BATCH * HID,  HID,
        T_STEPS, HID, ULEN, nullptr);

    // X2 = ctx @ W_ih2^T + (b_ih2+b_hh2)   [4096 x 2048 x 512]
    gemm_f32<true><<<dim3(G4H / 64, (T_STEPS * BATCH) / 64, 1), 256, 0, stream>>>(
        ctx, HID, 0, W_ih2, HID, 0, gates, G4H, 0,
        T_STEPS * BATCH, G4H, HID, bias2);

    // Layer-2 scan -> h2_all
    lstm_scan<<<256, 256, 0, stream>>>(gates, W_hh2, h0 + BATCH * HID, c0 + BATCH * HID,
                                       h2, flags + BAR_WORDS);

    // logits = h2 @ W_out^T + b_out   [4096 x 10000 x 512] -> d_out
    gemm_f32<true><<<dim3(cdiv(VOCAB, 64), (T_STEPS * BATCH) / 64, 1), 256, 0, stream>>>(
        h2, HID, 0, W_out, HID, 0, out, VOCAB, 0,
        T_STEPS * BATCH, VOCAB, HID, b_out);

    softmax_v<<<T_STEPS * BATCH, 256, 0, stream>>>(out);
}